// Round 2
// baseline (212.855 us; speedup 1.0000x reference)
//
#include <hip/hip_runtime.h>

#define NC   256
#define FHH  256
#define FWW  256
#define NOUT 7
#define NCELL 49

__global__ __launch_bounds__(256) void rroi_pool_kernel(
    const float* __restrict__ feat, const float* __restrict__ rois,
    float* __restrict__ out)
{
    const int cell = blockIdx.x;          // 0..48  (ph*7+pw)
    const int n    = blockIdx.y;          // roi
    const int c    = threadIdx.x;         // channel
    const int ph = cell / NOUT;
    const int pw = cell % NOUT;

    const float* r = rois + (size_t)n * 6;
    const int   idx = (int)r[0];
    const float x1 = r[1], y1 = r[2], x2 = r[3], y2 = r[4], th = r[5];
    const float cx = (x1 + x2) * 0.5f;
    const float cy = (y1 + y2) * 0.5f;
    const float w  = x2 - x1;
    const float h  = y2 - y1;
    const float cos_t = cosf(th), sin_t = sinf(th);

    // e(cos_t*w*0.5)*ux + e(sin_t*h*0.5)*uy  etc., replicated literally
    const float awx =  cos_t * w * 0.5f;
    const float bwy =  sin_t * h * 0.5f;
    const float cwx = -sin_t * w * 0.5f;
    const float dwy =  cos_t * h * 0.5f;

    const float* __restrict__ img =
        feat + ((size_t)idx * NC + c) * (size_t)(FHH * FWW);

    float m = -3.402823466e+38f;

#pragma unroll
    for (int dy = 0; dy < 2; ++dy) {
#pragma unroll
        for (int dx = 0; dx < 2; ++dx) {
            const int gy = 2 * ph + dy;       // row in 14x14 pre-pool grid
            const int gx = 2 * pw + dx;       // col
            const float uy = (2.0f * (float)gy + 1.0f) / 14.0f - 1.0f;
            const float ux = (2.0f * (float)gx + 1.0f) / 14.0f - 1.0f;

            const float px = cx + 16.0f * (awx * ux + bwy * uy);
            const float py = cy + 16.0f * (cwx * ux + dwy * uy);

            // replicate reference op sequence exactly
            const float gxn = 2.0f * px / 256.0f - 1.0f;
            const float gyn = 2.0f * py / 256.0f - 1.0f;
            const float ixf = ((gxn + 1.0f) * 256.0f - 1.0f) * 0.5f;
            const float iyf = ((gyn + 1.0f) * 256.0f - 1.0f) * 0.5f;

            const float ix0f = floorf(ixf);
            const float iy0f = floorf(iyf);
            const float wx = ixf - ix0f;
            const float wy = iyf - iy0f;
            const int ix0 = (int)ix0f;
            const int iy0 = (int)iy0f;
            const int ix1 = ix0 + 1;
            const int iy1 = iy0 + 1;

            const bool vx0 = (ix0 >= 0) & (ix0 < FWW);
            const bool vx1 = (ix1 >= 0) & (ix1 < FWW);
            const bool vy0 = (iy0 >= 0) & (iy0 < FHH);
            const bool vy1 = (iy1 >= 0) & (iy1 < FHH);

            float val = 0.0f;
            // condition is identical across all 256 lanes of the block
            // (depends only on roi+cell), so this branch is non-divergent
            // and skips all 4 gathers for fully-OOB samples.
            if ((vy0 | vy1) & (vx0 | vx1)) {
                const int xc0 = min(max(ix0, 0), FWW - 1);
                const int xc1 = min(max(ix1, 0), FWW - 1);
                const int yc0 = min(max(iy0, 0), FHH - 1);
                const int yc1 = min(max(iy1, 0), FHH - 1);
                const float v00 = img[yc0 * FWW + xc0] * (float)(vy0 & vx0);
                const float v01 = img[yc0 * FWW + xc1] * (float)(vy0 & vx1);
                const float v10 = img[yc1 * FWW + xc0] * (float)(vy1 & vx0);
                const float v11 = img[yc1 * FWW + xc1] * (float)(vy1 & vx1);
                val = v00 * ((1.0f - wy) * (1.0f - wx))
                    + v01 * ((1.0f - wy) * wx)
                    + v10 * (wy * (1.0f - wx))
                    + v11 * (wy * wx);
            }
            m = fmaxf(m, val);
        }
    }

    out[((size_t)n * NC + c) * NCELL + cell] = m;
}

extern "C" void kernel_launch(void* const* d_in, const int* in_sizes, int n_in,
                              void* d_out, int out_size, void* d_ws, size_t ws_size,
                              hipStream_t stream) {
    const float* feat = (const float*)d_in[0];
    const float* rois = (const float*)d_in[1];
    float* out = (float*)d_out;
    const int nrois = in_sizes[1] / 6;   // 512
    dim3 grid(NCELL, nrois);
    rroi_pool_kernel<<<grid, 256, 0, stream>>>(feat, rois, out);
}

// Round 3
// 179.634 us; speedup vs baseline: 1.1849x; 1.1849x over previous
//
#include <hip/hip_runtime.h>
#include <float.h>

#define NC    256
#define FHH   256
#define FWW   256
#define NOUT  7
#define NCELL 49
#define NSAMP (NCELL * 4)   // 196 pre-pool samples per roi

// One block per roi. Stage 1: threads 0..195 each compute one sample record
// (4 clipped gather offsets + 4 valid-premultiplied bilinear weights) using
// the exact reference op sequence. Stage 2: thread c = channel; loops 49
// cells doing gathers only; outputs staged in LDS, written coalesced.
__global__ __launch_bounds__(256) void rroi_pool_roi_kernel(
    const float* __restrict__ feat, const float* __restrict__ rois,
    float* __restrict__ out)
{
    __shared__ int4   s_off[NSAMP];
    __shared__ float4 s_wt[NSAMP];
    __shared__ int    s_any[NSAMP];
    __shared__ float  s_out[NC * NCELL];   // 50176 floats = 49 KiB

    const int n = blockIdx.x;
    const int tid = threadIdx.x;
    const float* __restrict__ r = rois + (size_t)n * 6;

    if (tid < NSAMP) {
        const int cell = tid >> 2;
        const int sub  = tid & 3;
        const int ph = cell / NOUT, pw = cell % NOUT;
        const int dy = sub >> 1,    dx = sub & 1;
        const int gy = 2 * ph + dy;
        const int gx = 2 * pw + dx;

        const float x1 = r[1], y1 = r[2], x2 = r[3], y2 = r[4], th = r[5];
        const float cx = (x1 + x2) * 0.5f;
        const float cy = (y1 + y2) * 0.5f;
        const float w  = x2 - x1;
        const float h  = y2 - y1;
        const float cos_t = cosf(th), sin_t = sinf(th);
        const float awx =  cos_t * w * 0.5f;
        const float bwy =  sin_t * h * 0.5f;
        const float cwx = -sin_t * w * 0.5f;
        const float dwy =  cos_t * h * 0.5f;

        const float uy = (2.0f * (float)gy + 1.0f) / 14.0f - 1.0f;
        const float ux = (2.0f * (float)gx + 1.0f) / 14.0f - 1.0f;

        const float px = cx + 16.0f * (awx * ux + bwy * uy);
        const float py = cy + 16.0f * (cwx * ux + dwy * uy);

        // replicate reference op sequence exactly
        const float gxn = 2.0f * px / 256.0f - 1.0f;
        const float gyn = 2.0f * py / 256.0f - 1.0f;
        const float ixf = ((gxn + 1.0f) * 256.0f - 1.0f) * 0.5f;
        const float iyf = ((gyn + 1.0f) * 256.0f - 1.0f) * 0.5f;

        const float ix0f = floorf(ixf);
        const float iy0f = floorf(iyf);
        const float wx = ixf - ix0f;
        const float wy = iyf - iy0f;
        const int ix0 = (int)ix0f;
        const int iy0 = (int)iy0f;
        const int ix1 = ix0 + 1;
        const int iy1 = iy0 + 1;

        const bool vx0 = (ix0 >= 0) & (ix0 < FWW);
        const bool vx1 = (ix1 >= 0) & (ix1 < FWW);
        const bool vy0 = (iy0 >= 0) & (iy0 < FHH);
        const bool vy1 = (iy1 >= 0) & (iy1 < FHH);

        const int xc0 = min(max(ix0, 0), FWW - 1);
        const int xc1 = min(max(ix1, 0), FWW - 1);
        const int yc0 = min(max(iy0, 0), FHH - 1);
        const int yc1 = min(max(iy1, 0), FHH - 1);

        s_off[tid] = make_int4(yc0 * FWW + xc0, yc0 * FWW + xc1,
                               yc1 * FWW + xc0, yc1 * FWW + xc1);
        // valid premultiplied into weight: exact (valid ∈ {0,1})
        s_wt[tid] = make_float4(((1.0f - wy) * (1.0f - wx)) * (float)(vy0 & vx0),
                                ((1.0f - wy) * wx)          * (float)(vy0 & vx1),
                                (wy * (1.0f - wx))          * (float)(vy1 & vx0),
                                (wy * wx)                   * (float)(vy1 & vx1));
        s_any[tid] = (int)((vy0 | vy1) & (vx0 | vx1));
    }
    __syncthreads();

    // stage 2: one channel per thread
    const int c = tid;
    const int idx = (int)r[0];   // uniform scalar load
    const float* __restrict__ img =
        feat + ((size_t)idx * NC + c) * (size_t)(FHH * FWW);

    for (int cell = 0; cell < NCELL; ++cell) {
        float m = -FLT_MAX;
#pragma unroll
        for (int sub = 0; sub < 4; ++sub) {
            const int s = cell * 4 + sub;
            float val = 0.0f;
            if (s_any[s]) {             // block-uniform branch
                const int4   o = s_off[s];   // LDS broadcast
                const float4 wv = s_wt[s];
                val = img[o.x] * wv.x + img[o.y] * wv.y
                    + img[o.z] * wv.z + img[o.w] * wv.w;
            }
            m = fmaxf(m, val);
        }
        s_out[c * NCELL + cell] = m;    // stride-49: 2-way bank alias = free
    }
    __syncthreads();

    // coalesced float4 write of this roi's contiguous 50176-float region
    float4* __restrict__ dst = (float4*)(out + (size_t)n * (NC * NCELL));
    const float4* __restrict__ src = (const float4*)s_out;
#pragma unroll
    for (int i = tid; i < (NC * NCELL) / 4; i += 256)
        dst[i] = src[i];
}

extern "C" void kernel_launch(void* const* d_in, const int* in_sizes, int n_in,
                              void* d_out, int out_size, void* d_ws, size_t ws_size,
                              hipStream_t stream) {
    const float* feat = (const float*)d_in[0];
    const float* rois = (const float*)d_in[1];
    float* out = (float*)d_out;
    const int nrois = in_sizes[1] / 6;   // 512
    rroi_pool_roi_kernel<<<nrois, 256, 0, stream>>>(feat, rois, out);
}